// Round 8
// baseline (503.159 us; speedup 1.0000x reference)
//
#include <hip/hip_runtime.h>

#define T_STEPS 256
#define B_SZ 8
#define HID 256

typedef _Float16 hv2 __attribute__((ext_vector_type(2)));
typedef _Float16 f16x4 __attribute__((ext_vector_type(4)));
typedef float f32x4 __attribute__((ext_vector_type(4)));
union H2U { hv2 h; unsigned u; };
union U2F { uint2 u; f16x4 h; };
__device__ inline hv2 u2h(unsigned u){ H2U c; c.u = u; return c.h; }
__device__ inline unsigned h2u(hv2 h){ H2U c; c.h = h; return c.u; }
__device__ inline hv2 relu2(hv2 v){
  unsigned u = h2u(v);
  unsigned s = (u & 0x80008000u) >> 15;
  u &= ~(s * 0xFFFFu);
  return u2h(u);
}
__device__ inline unsigned packh2f(float lo, float hi){
  hv2 h; h.x = (_Float16)lo; h.y = (_Float16)hi; return h2u(h);
}

// ---- workspace layout (dword offsets) ----
#define OFF_XW   0                 // (T,B,256) fused input projection  524288
#define OFF_HH   524288            // (T,B,256) hidden history          524288
#define OFF_WFT  1141760           // WfuseT[m][j] 128*256
#define OFF_BF   1174528           // bfuse[j] 256
#define OFF_D1T  1174784           // dec_w1T 256*128
#define OFF_D2T  1207552           // dec_w2T 128*64
#define OFF_D3T  1215744           // dec_w3T 64*6
#define OFF_W1P  1216128           // conv1 packed [k=27][pair=16] 432 dw
#define OFF_W2F  1216560           // conv2 B-frags [2][9][4][64][2] 9216 dw
#define OFF_W3F  1225776           // conv3 B-frags [36][8][64][2] 36864 dw
#define OFF_WRP  1262640           // ltc_wr fp16 pairs [q=4][j=256][i=32] 32768 dw

// ---------------- prep ----------------
__global__ __launch_bounds__(256) void prep_kernel(
    const float* __restrict__ conv1_w, const float* __restrict__ conv2_w,
    const float* __restrict__ conv3_w, const float* __restrict__ enc_w,
    const float* __restrict__ enc_b,  const float* __restrict__ ltc_wi,
    const float* __restrict__ ltc_b,  const float* __restrict__ ltc_wr,
    const float* __restrict__ dec_w1,
    const float* __restrict__ dec_w2, const float* __restrict__ dec_w3,
    float* __restrict__ ws)
{
  int gtid = blockIdx.x * 256 + threadIdx.x;
  int nth = gridDim.x * 256;
  unsigned* wsu = (unsigned*)ws;
  for (int e = gtid; e < 128 * 256; e += nth) {
    int j = e >> 7, m = e & 127;
    float s = 0.f;
    for (int k = 0; k < 256; ++k) s = fmaf(ltc_wi[j*256 + k], enc_w[k*128 + m], s);
    ws[OFF_WFT + m*256 + j] = s;
  }
  for (int e = gtid; e < 256; e += nth) {
    float s = ltc_b[e];
    for (int k = 0; k < 256; ++k) s = fmaf(ltc_wi[e*256 + k], enc_b[k], s);
    ws[OFF_BF + e] = s;
  }
  for (int e = gtid; e < 27*16; e += nth) { int k = e>>4, p = e&15;
    wsu[OFF_W1P+e] = packh2f(conv1_w[(2*p)*27 + k], conv1_w[(2*p+1)*27 + k]); }
  // conv2 B fragments: e = (((hp*9+kt)*4+nt)*64 + l)*2 + dpair
  for (int e = gtid; e < 9216; e += nth) {
    int dpair = e & 1;
    int tmp = e >> 1;
    int l = tmp & 63; tmp >>= 6;
    int nt = tmp & 3; tmp >>= 2;
    int kt = tmp % 9, hp = tmp / 9;
    int oc = nt*16 + (l & 15);
    int ic = hp*16 + ((l>>4)<<2) + (dpair<<1);
    int ky = kt/3, kx = kt%3;
    wsu[OFF_W2F + e] = packh2f(conv2_w[((oc*32 + ic)*3 + ky)*3 + kx],
                               conv2_w[((oc*32 + ic+1)*3 + ky)*3 + kx]);
  }
  // conv3 B fragments: e = ((kt*8+nt)*64 + l)*2 + dpair
  for (int e = gtid; e < 36864; e += nth) {
    int dpair = e & 1;
    int tmp = e >> 1;
    int l = tmp & 63; tmp >>= 6;
    int nt = tmp & 7; tmp >>= 3;
    int kt = tmp;
    int kyx = kt >> 2;
    int ky = kyx/3, kx = kyx%3;
    int ic = ((kt & 3) << 4) + ((l>>4)<<2) + (dpair<<1);
    int oc = nt*16 + (l & 15);
    wsu[OFF_W3F + e] = packh2f(conv3_w[((oc*64 + ic)*3 + ky)*3 + kx],
                               conv3_w[((oc*64 + ic+1)*3 + ky)*3 + kx]);
  }
  // ltc_wr fp16 pairs
  for (int e = gtid; e < 32768; e += nth) {
    int i = e & 31;
    int j = (e >> 5) & 255;
    int q = e >> 13;
    wsu[OFF_WRP + e] = packh2f(ltc_wr[j*256 + q*64 + 2*i],
                               ltc_wr[j*256 + q*64 + 2*i + 1]);
  }
  for (int e = gtid; e < 256*128;e += nth) { int k = e>>7, i = e&127; ws[OFF_D1T+e] = dec_w1[i*256 + k]; }
  for (int e = gtid; e < 128*64; e += nth) { int k = e>>6, i = e&63;  ws[OFF_D2T+e] = dec_w2[i*128 + k]; }
  for (int e = gtid; e < 64*6;   e += nth) { int k = e/6,  o = e%6;   ws[OFF_D3T+e] = dec_w3[o*64 + k]; }
}

// ---------------- fused per-frame CNN encoder: fp16 conv1 + MFMA conv2/conv3 ----------------
// Dynamic LDS 52928B: buf0 8192dw (act1 -> act2) | w3buf 4096dw (conv3-B half-chunk dbuf)
//                     | w1s 432dw | fmp 512 floats.  3 blocks/CU target.
__global__ __launch_bounds__(256, 3) void enc_kernel(
    const float* __restrict__ frames,
    const float* __restrict__ b1, const float* __restrict__ b2,
    const float* __restrict__ b3, float* __restrict__ ws)
{
  extern __shared__ __align__(16) unsigned lds[];
  unsigned* buf0  = lds;            // conv1 out (swizzled ch-last), later act2
  unsigned* w3buf = lds + 8192;     // conv3-B half-chunk double buffer (2 x 8KB)
  unsigned* w1s   = lds + 12288;    // conv1 weights
  float* fmp = (float*)(lds + 12720);

  const int tid = threadIdx.x;
  const int l   = tid & 63;
  const int w   = tid >> 6;
  const int kg  = l >> 4;
  const int lc  = l & 15;
  const int bt  = blockIdx.x;
  const int b   = bt >> 8, t = bt & 255;
  const float* fr = frames + (size_t)bt * 12288;
  const unsigned* wsu = (const unsigned*)ws;
  const uint2* w2f = (const uint2*)(wsu + OFF_W2F);
  const uint4* w3src = (const uint4*)(wsu + OFF_W3F);

  // stage conv1 weights only (conv2-B read direct from L2)
  if (tid < 216) ((uint2*)w1s)[tid] = ((const uint2*)(wsu + OFF_W1P))[tid];
  __syncthreads();

  f32x4 acc2[4][4];
  #pragma unroll
  for (int mi = 0; mi < 4; ++mi)
    #pragma unroll
    for (int nt = 0; nt < 4; ++nt) {
      float bb = b2[nt*16 + lc];
      acc2[mi][nt] = (f32x4){bb, bb, bb, bb};
    }

  for (int hp = 0; hp < 2; ++hp) {
    // ---- conv1 half (VALU fp16), swizzled channel-last write into buf0 ----
    for (int p = 0; p < 4; ++p) {
      int pos = p*256 + tid;
      int y = pos >> 5, x = pos & 31;
      hv2 a1[8];
      #pragma unroll
      for (int o = 0; o < 8; ++o) { a1[o].x = (_Float16)b1[16*hp+2*o]; a1[o].y = (_Float16)b1[16*hp+2*o+1]; }
      for (int ic = 0; ic < 3; ++ic)
        for (int ky = 0; ky < 3; ++ky) {
          int iy = 2*y - 1 + ky;
          bool rok = (unsigned)iy < 64u;
          for (int kx = 0; kx < 3; ++kx) {
            int ix = 2*x - 1 + kx;
            float v = (rok && (unsigned)ix < 64u) ? fr[ic*4096 + iy*64 + ix] : 0.f;
            _Float16 hf = (_Float16)v;
            hv2 vs; vs.x = hf; vs.y = hf;
            int k = ic*9 + ky*3 + kx;
            uint4 wa = ((uint4*)w1s)[k*4 + hp*2];
            uint4 wb = ((uint4*)w1s)[k*4 + hp*2 + 1];
            a1[0] = vs * u2h(wa.x) + a1[0];
            a1[1] = vs * u2h(wa.y) + a1[1];
            a1[2] = vs * u2h(wa.z) + a1[2];
            a1[3] = vs * u2h(wa.w) + a1[3];
            a1[4] = vs * u2h(wb.x) + a1[4];
            a1[5] = vs * u2h(wb.y) + a1[5];
            a1[6] = vs * u2h(wb.z) + a1[6];
            a1[7] = vs * u2h(wb.w) + a1[7];
          }
        }
      unsigned r0 = h2u(relu2(a1[0])), r1 = h2u(relu2(a1[1]));
      unsigned r2 = h2u(relu2(a1[2])), r3 = h2u(relu2(a1[3]));
      unsigned r4 = h2u(relu2(a1[4])), r5 = h2u(relu2(a1[5]));
      unsigned r6 = h2u(relu2(a1[6])), r7 = h2u(relu2(a1[7]));
      int s = pos & 3;
      uint4 v0, v1;
      if (s & 1) { v0 = make_uint4(r2,r3,r0,r1); v1 = make_uint4(r6,r7,r4,r5); }
      else       { v0 = make_uint4(r0,r1,r2,r3); v1 = make_uint4(r4,r5,r6,r7); }
      int sl = (s >> 1) & 1;
      ((uint4*)buf0)[pos*2 + sl]     = v0;
      ((uint4*)buf0)[pos*2 + (1^sl)] = v1;
    }
    __syncthreads();
    // ---- conv2 half (MFMA): B-frags direct from L2; wave w owns M-tiles w*4.. ----
    #pragma unroll
    for (int ky = 0; ky < 3; ++ky)
      #pragma unroll
      for (int kx = 0; kx < 3; ++kx) {
        int kt = ky*3 + kx;
        U2F bf[4];
        #pragma unroll
        for (int nt = 0; nt < 4; ++nt)
          bf[nt].u = w2f[(((hp*9 + kt)*4 + nt)<<6) + l];
        #pragma unroll
        for (int mi = 0; mi < 4; ++mi) {
          int mt = w*4 + mi;
          int iy = 2*mt - 1 + ky;
          if (iy >= 0) {
            int ix = 2*lc - 1 + kx;
            bool okx = (unsigned)ix < 32u;
            int pos1 = iy*32 + (okx ? ix : 0);
            U2F av; av.u = ((const uint2*)buf0)[pos1*4 + (kg ^ (pos1 & 3))];
            if (!okx) { av.u.x = 0u; av.u.y = 0u; }
            #pragma unroll
            for (int nt = 0; nt < 4; ++nt)
              acc2[mi][nt] = __builtin_amdgcn_mfma_f32_16x16x16f16(av.h, bf[nt].h, acc2[mi][nt], 0, 0, 0);
          }
        }
      }
    __syncthreads();   // act1 fully consumed (after hp=1: buf0 free for act2)
  }

  // ---- act2 (relu, swizzled ch-last fp16) into buf0; pre-stage conv3-B half-chunk 0 ----
  {
    uint4 s0a = w3src[tid];
    uint4 s0b = w3src[256 + tid];
    _Float16* act2h = (_Float16*)buf0;
    #pragma unroll
    for (int mi = 0; mi < 4; ++mi)
      #pragma unroll
      for (int nt = 0; nt < 4; ++nt)
        #pragma unroll
        for (int i = 0; i < 4; ++i) {
          int pos = (w*4 + mi)*16 + 4*kg + i;
          int oc = nt*16 + lc;
          float vv = fmaxf(acc2[mi][nt][i], 0.f);
          int ocp = (((oc >> 2) ^ (pos & 7)) << 2) + (oc & 3);
          act2h[pos*64 + ocp] = (_Float16)vv;
        }
    ((uint4*)w3buf)[tid] = s0a;
    ((uint4*)w3buf)[256 + tid] = s0b;
  }

  f32x4 acc3[8];
  #pragma unroll
  for (int nt = 0; nt < 8; ++nt) { float bb = b3[nt*16 + lc]; acc3[nt] = (f32x4){bb, bb, bb, bb}; }
  const int y3 = (w*16 + lc) >> 3, x3 = lc & 7;
  __syncthreads();

  // ---- conv3 (MFMA): 18 half-chunks (2 K-tiles each), dbuf reg->LDS staging ----
  for (int cc = 0; cc < 18; ++cc) {
    uint4 st0, st1;
    if (cc < 17) {
      st0 = w3src[(cc+1)*512 + tid];
      st1 = w3src[(cc+1)*512 + 256 + tid];
    }
    int kyx = cc >> 1;
    int ky = kyx / 3, kx = kyx % 3;
    int iy = 2*y3 - 1 + ky, ix = 2*x3 - 1 + kx;
    bool ok = ((unsigned)iy < 16u) && ((unsigned)ix < 16u);
    int posIn = (ok ? iy : 0)*16 + (ok ? ix : 0);
    int sw = posIn & 7;
    const uint2* bvp = (const uint2*)w3buf + (cc & 1)*1024;
    #pragma unroll
    for (int k2 = 0; k2 < 2; ++k2) {
      int kt = 2*cc + k2;
      int icb = (kt & 3)*4 + kg;
      U2F av; av.u = ((const uint2*)buf0)[posIn*16 + (icb ^ sw)];
      if (!ok) { av.u.x = 0u; av.u.y = 0u; }
      #pragma unroll
      for (int nt = 0; nt < 8; ++nt) {
        U2F bv; bv.u = bvp[((k2*8 + nt)<<6) + l];
        acc3[nt] = __builtin_amdgcn_mfma_f32_16x16x16f16(av.h, bv.h, acc3[nt], 0, 0, 0);
      }
    }
    if (cc < 17) {
      ((uint4*)w3buf)[((cc+1)&1)*512 + tid] = st0;
      ((uint4*)w3buf)[((cc+1)&1)*512 + 256 + tid] = st1;
    }
    __syncthreads();
  }

  // ---- relu + spatial mean + fused encoder projection ----
  #pragma unroll
  for (int nt = 0; nt < 8; ++nt) {
    float s = 0.f;
    #pragma unroll
    for (int i = 0; i < 4; ++i) s += fmaxf(acc3[nt][i], 0.f);
    s += __shfl_xor(s, 16);
    s += __shfl_xor(s, 32);
    if (l < 16) fmp[w*128 + nt*16 + l] = s;
  }
  __syncthreads();
  if (tid < 128) {
    float s = fmp[tid] + fmp[128 + tid] + fmp[256 + tid] + fmp[384 + tid];
    fmp[tid] = s * (1.f/64.f);
  }
  __syncthreads();
  {
    float accx = ws[OFF_BF + tid];
    const float* wfT = ws + OFF_WFT;
    for (int m = 0; m < 128; ++m) accx = fmaf(fmp[m], wfT[m*256 + tid], accx);
    ws[OFF_XW + (t*B_SZ + b)*HID + tid] = accx;
  }
}

// ---------------- sequential LTC scan: 1 block per batch, fp16 reg-resident weights ----------------
__global__ __launch_bounds__(1024) void scan_kernel(
    const float* __restrict__ tau, const float* __restrict__ av,
    const float* __restrict__ h0,
    float* __restrict__ ws, float* __restrict__ outh)
{
  const int b = blockIdx.x;
  const int tid = threadIdx.x;
  const int j = tid & 255, q = tid >> 8;
  __shared__ float hf[256];
  __shared__ unsigned hp16[128];
  __shared__ float part[4][256];
  __shared__ float hbuf[16*256];

  uint4 wv[8];
  {
    const uint4* wp = (const uint4*)((const unsigned*)ws + OFF_WRP + (q*256 + j)*32);
    #pragma unroll
    for (int r = 0; r < 8; ++r) wv[r] = wp[r];
  }
  const float tinv = 1.f / tau[j];
  const float aj = av[j];
  const float* xw = ws + OFF_XW;
  float* hh = ws + OFF_HH;

  {
    float hv0 = h0[b*256 + j];
    float hvn = __shfl_xor(hv0, 1);
    if (q == 0) {
      hf[j] = hv0;
      if (!(j & 1)) hp16[j >> 1] = packh2f(hv0, hvn);
    }
  }
  float xw_pref = xw[(0*B_SZ + b)*HID + j];
  __syncthreads();

  for (int t = 0; t < T_STEPS; ++t) {
    float xwv = xw_pref;
    xw_pref = xw[((t+1)*B_SZ + b)*HID + j];
    hv2 acc = {(_Float16)0.f, (_Float16)0.f};
    const uint4* hq = (const uint4*)hp16 + q*8;
    #pragma unroll
    for (int r = 0; r < 8; ++r) {
      uint4 hvp = hq[r];
      acc = u2h(hvp.x) * u2h(wv[r].x) + acc;
      acc = u2h(hvp.y) * u2h(wv[r].y) + acc;
      acc = u2h(hvp.z) * u2h(wv[r].z) + acc;
      acc = u2h(hvp.w) * u2h(wv[r].w) + acc;
    }
    float hv0 = hf[j];
    part[q][j] = (float)acc.x + (float)acc.y;
    __syncthreads();
    float pre = part[0][j] + part[1][j] + part[2][j] + part[3][j] + xwv;
    float f = 1.f - 2.f / (1.f + __expf(2.f * pre));
    float hn = fmaf(0.1f, fmaf(-(tinv + f), hv0, f * aj), hv0);
    float hnn = __shfl_xor(hn, 1);
    if (q == 0) {
      hf[j] = hn;
      hbuf[(t & 15)*256 + j] = hn;
      if (!(j & 1)) hp16[j >> 1] = packh2f(hn, hnn);
    }
    __syncthreads();
    if ((t & 15) == 15) {
      int base = t - 15;
      int st = tid >> 6;
      int col = (tid & 63) << 2;
      *(float4*)(hh + ((base + st)*B_SZ + b)*HID + col) = *(float4*)(hbuf + st*256 + col);
    }
  }
  if (q == 0) outh[b*HID + j] = hf[j];
}

// ---------------- decoder MLP over all (t,b), parallel ----------------
__global__ __launch_bounds__(256) void dec_kernel(
    const float* __restrict__ db1, const float* __restrict__ db2,
    const float* __restrict__ db3, const float* __restrict__ ws,
    float* __restrict__ outc)
{
  const int bid = blockIdx.x;
  const int b = bid >> 8, t = bid & 255;
  const int tid = threadIdx.x;
  __shared__ float hloc[256];
  __shared__ float p1[2][128];
  __shared__ float y1s[128];
  __shared__ float p2[4][64];
  __shared__ float y2s[64];
  const float* hh  = ws + OFF_HH + (t*B_SZ + b)*HID;
  const float* d1T = ws + OFF_D1T;
  const float* d2T = ws + OFF_D2T;
  const float* d3T = ws + OFF_D3T;
  hloc[tid] = hh[tid];
  __syncthreads();
  {
    int i = tid & 127, hf = tid >> 7;
    float s = 0.f;
    for (int k = hf*128; k < hf*128 + 128; ++k) s = fmaf(hloc[k], d1T[k*128 + i], s);
    p1[hf][i] = s;
  }
  __syncthreads();
  if (tid < 128) y1s[tid] = fmaxf(p1[0][tid] + p1[1][tid] + db1[tid], 0.f);
  __syncthreads();
  {
    int i = tid & 63, r = tid >> 6;
    float s = 0.f;
    for (int k = r*32; k < r*32 + 32; ++k) s = fmaf(y1s[k], d2T[k*64 + i], s);
    p2[r][i] = s;
  }
  __syncthreads();
  if (tid < 64) y2s[tid] = fmaxf(p2[0][tid] + p2[1][tid] + p2[2][tid] + p2[3][tid] + db2[tid], 0.f);
  __syncthreads();
  if (tid < 6) {
    float s = db3[tid];
    for (int k = 0; k < 64; ++k) s = fmaf(y2s[k], d3T[k*6 + tid], s);
    outc[(b*T_STEPS + t)*6 + tid] = s;
  }
}

extern "C" void kernel_launch(void* const* d_in, const int* in_sizes, int n_in,
                              void* d_out, int out_size, void* d_ws, size_t ws_size,
                              hipStream_t stream)
{
  const float* frames = (const float*)d_in[0];
  const float* h0   = (const float*)d_in[1];
  const float* c1w  = (const float*)d_in[2];
  const float* c1b  = (const float*)d_in[3];
  const float* c2w  = (const float*)d_in[4];
  const float* c2b  = (const float*)d_in[5];
  const float* c3w  = (const float*)d_in[6];
  const float* c3b  = (const float*)d_in[7];
  const float* encw = (const float*)d_in[8];
  const float* encb = (const float*)d_in[9];
  const float* wr   = (const float*)d_in[10];
  const float* wi   = (const float*)d_in[11];
  const float* lb   = (const float*)d_in[12];
  const float* ltau = (const float*)d_in[13];
  const float* la   = (const float*)d_in[14];
  const float* dw1  = (const float*)d_in[15];
  const float* db1  = (const float*)d_in[16];
  const float* dw2  = (const float*)d_in[17];
  const float* db2  = (const float*)d_in[18];
  const float* dw3  = (const float*)d_in[19];
  const float* db3  = (const float*)d_in[20];
  float* out = (float*)d_out;
  float* ws  = (float*)d_ws;

  hipLaunchKernelGGL(prep_kernel, dim3(256), dim3(256), 0, stream,
                     c1w, c2w, c3w, encw, encb, wi, lb, wr, dw1, dw2, dw3, ws);
  hipLaunchKernelGGL(enc_kernel, dim3(2048), dim3(256), 52928, stream,
                     frames, c1b, c2b, c3b, ws);
  hipLaunchKernelGGL(scan_kernel, dim3(B_SZ), dim3(1024), 0, stream,
                     ltau, la, h0, ws, out + 12288);
  hipLaunchKernelGGL(dec_kernel, dim3(2048), dim3(256), 0, stream,
                     db1, db2, db3, ws, out);
}

// Round 9
// 408.477 us; speedup vs baseline: 1.2318x; 1.2318x over previous
//
#include <hip/hip_runtime.h>

#define T_STEPS 256
#define B_SZ 8
#define HID 256

typedef _Float16 hv2 __attribute__((ext_vector_type(2)));
typedef _Float16 f16x4 __attribute__((ext_vector_type(4)));
typedef float f32x4 __attribute__((ext_vector_type(4)));
union H2U { hv2 h; unsigned u; };
union U2F { uint2 u; f16x4 h; };
__device__ inline hv2 u2h(unsigned u){ H2U c; c.u = u; return c.h; }
__device__ inline unsigned h2u(hv2 h){ H2U c; c.h = h; return c.u; }
__device__ inline hv2 relu2(hv2 v){
  unsigned u = h2u(v);
  unsigned s = (u & 0x80008000u) >> 15;
  u &= ~(s * 0xFFFFu);
  return u2h(u);
}
__device__ inline unsigned packh2f(float lo, float hi){
  hv2 h; h.x = (_Float16)lo; h.y = (_Float16)hi; return h2u(h);
}

// ---- workspace layout (dword offsets) ----
#define OFF_XW   0                 // (T,B,256) fused input projection  524288
#define OFF_HH   524288            // (T,B,256) hidden history          524288
#define OFF_WFT  1141760           // WfuseT[m][j] 128*256
#define OFF_BF   1174528           // bfuse[j] 256
#define OFF_D1T  1174784           // dec_w1T 256*128
#define OFF_D2T  1207552           // dec_w2T 128*64
#define OFF_D3T  1215744           // dec_w3T 64*6
#define OFF_W1P  1216128           // conv1 packed [k=27][pair=16] 432 dw
#define OFF_W2F  1216560           // conv2 B-frags [hp*9+kt][l][nt][2] 9216 dw
#define OFF_W3F  1225776           // conv3 B-frags [36][8][64][2] 36864 dw
#define OFF_WRP  1262640           // ltc_wr fp16 pairs [q=4][j=256][i=32] 32768 dw

// ---- enc LDS layout (dword offsets inside dynamic LDS) ----
// buf0:  0..8192      act1 (swizzled ch-last) -> act2
// frH:   8192..15320  padded fp16 frame [3][66][72] (7128 dw); ALIASES w3buf (4096 dw)
// w1s:   15320..15752 conv1 weights
// fmp:   15752..16264 spatial-mean scratch
#define ENC_LDS_DW 16264

// ---------------- prep ----------------
__global__ __launch_bounds__(256) void prep_kernel(
    const float* __restrict__ conv1_w, const float* __restrict__ conv2_w,
    const float* __restrict__ conv3_w, const float* __restrict__ enc_w,
    const float* __restrict__ enc_b,  const float* __restrict__ ltc_wi,
    const float* __restrict__ ltc_b,  const float* __restrict__ ltc_wr,
    const float* __restrict__ dec_w1,
    const float* __restrict__ dec_w2, const float* __restrict__ dec_w3,
    float* __restrict__ ws)
{
  int gtid = blockIdx.x * 256 + threadIdx.x;
  int nth = gridDim.x * 256;
  unsigned* wsu = (unsigned*)ws;
  for (int e = gtid; e < 128 * 256; e += nth) {
    int j = e >> 7, m = e & 127;
    float s = 0.f;
    for (int k = 0; k < 256; ++k) s = fmaf(ltc_wi[j*256 + k], enc_w[k*128 + m], s);
    ws[OFF_WFT + m*256 + j] = s;
  }
  for (int e = gtid; e < 256; e += nth) {
    float s = ltc_b[e];
    for (int k = 0; k < 256; ++k) s = fmaf(ltc_wi[e*256 + k], enc_b[k], s);
    ws[OFF_BF + e] = s;
  }
  for (int e = gtid; e < 27*16; e += nth) { int k = e>>4, p = e&15;
    wsu[OFF_W1P+e] = packh2f(conv1_w[(2*p)*27 + k], conv1_w[(2*p+1)*27 + k]); }
  // conv2 B fragments, nt-innermost: e = ((g*64 + l)*4 + nt)*2 + dpair, g = hp*9+kt
  for (int e = gtid; e < 9216; e += nth) {
    int dpair = e & 1;
    int nt = (e >> 1) & 3;
    int l  = (e >> 3) & 63;
    int g  = e >> 9;
    int kt = g % 9, hp = g / 9;
    int oc = nt*16 + (l & 15);
    int ic = hp*16 + ((l>>4)<<2) + (dpair<<1);
    int ky = kt/3, kx = kt%3;
    wsu[OFF_W2F + e] = packh2f(conv2_w[((oc*32 + ic)*3 + ky)*3 + kx],
                               conv2_w[((oc*32 + ic+1)*3 + ky)*3 + kx]);
  }
  // conv3 B fragments: e = ((kt*8+nt)*64 + l)*2 + dpair   (unchanged)
  for (int e = gtid; e < 36864; e += nth) {
    int dpair = e & 1;
    int tmp = e >> 1;
    int l = tmp & 63; tmp >>= 6;
    int nt = tmp & 7; tmp >>= 3;
    int kt = tmp;
    int kyx = kt >> 2;
    int ky = kyx/3, kx = kyx%3;
    int ic = ((kt & 3) << 4) + ((l>>4)<<2) + (dpair<<1);
    int oc = nt*16 + (l & 15);
    wsu[OFF_W3F + e] = packh2f(conv3_w[((oc*64 + ic)*3 + ky)*3 + kx],
                               conv3_w[((oc*64 + ic+1)*3 + ky)*3 + kx]);
  }
  // ltc_wr fp16 pairs
  for (int e = gtid; e < 32768; e += nth) {
    int i = e & 31;
    int j = (e >> 5) & 255;
    int q = e >> 13;
    wsu[OFF_WRP + e] = packh2f(ltc_wr[j*256 + q*64 + 2*i],
                               ltc_wr[j*256 + q*64 + 2*i + 1]);
  }
  for (int e = gtid; e < 256*128;e += nth) { int k = e>>7, i = e&127; ws[OFF_D1T+e] = dec_w1[i*256 + k]; }
  for (int e = gtid; e < 128*64; e += nth) { int k = e>>6, i = e&63;  ws[OFF_D2T+e] = dec_w2[i*128 + k]; }
  for (int e = gtid; e < 64*6;   e += nth) { int k = e/6,  o = e%6;   ws[OFF_D3T+e] = dec_w3[o*64 + k]; }
}

// ---------------- fused per-frame CNN encoder ----------------
__global__ __launch_bounds__(256, 2) void enc_kernel(
    const float* __restrict__ frames,
    const float* __restrict__ b1, const float* __restrict__ b2,
    const float* __restrict__ b3, float* __restrict__ ws)
{
  extern __shared__ __align__(16) unsigned lds[];
  unsigned* buf0  = lds;            // act1 (swizzled ch-last), later act2
  unsigned* frH   = lds + 8192;     // padded fp16 frame [3][66][72]; aliases w3buf
  unsigned* w3buf = lds + 8192;     // conv3-B half-chunk double buffer (2 x 8KB)
  unsigned* w1s   = lds + 15320;    // conv1 weights
  float* fmp = (float*)(lds + 15752);
  _Float16* frHh = (_Float16*)frH;

  const int tid = threadIdx.x;
  const int l   = tid & 63;
  const int w   = tid >> 6;
  const int kg  = l >> 4;
  const int lc  = l & 15;
  const int bt  = blockIdx.x;
  const int b   = bt >> 8, t = bt & 255;
  const float* fr = frames + (size_t)bt * 12288;
  const unsigned* wsu = (const unsigned*)ws;
  const uint4* w2f4 = (const uint4*)(wsu + OFF_W2F);
  const uint4* w3src = (const uint4*)(wsu + OFF_W3F);

  // phase 0a: zero padded frame + stage conv1 weights
  {
    uint4 z4 = make_uint4(0u, 0u, 0u, 0u);
    for (int i = tid; i < 1782; i += 256) ((uint4*)frH)[i] = z4;
    if (tid < 216) ((uint2*)w1s)[tid] = ((const uint2*)(wsu + OFF_W1P))[tid];
  }
  __syncthreads();
  // phase 0b: stage frame interior as fp16 (coalesced float4 loads)
  {
    const float4* fr4 = (const float4*)fr;
    #pragma unroll
    for (int p = 0; p < 12; ++p) {
      int fidx = p*256 + tid;
      float4 v = fr4[fidx];
      int ic = fidx >> 10, rem = fidx & 1023;
      int iy = rem >> 4, xq = rem & 15;
      int dw = ic*2376 + (iy+1)*36 + 2*xq + 2;
      uint2 pk;
      pk.x = packh2f(v.x, v.y);
      pk.y = packh2f(v.z, v.w);
      *(uint2*)(frH + dw) = pk;
    }
  }
  __syncthreads();

  f32x4 acc2[4][4];
  #pragma unroll
  for (int mi = 0; mi < 4; ++mi)
    #pragma unroll
    for (int nt = 0; nt < 4; ++nt) {
      float bb = b2[nt*16 + lc];
      acc2[mi][nt] = (f32x4){bb, bb, bb, bb};
    }

  for (int hp = 0; hp < 2; ++hp) {
    // ---- conv1 half: taps from padded LDS frame, compile-time offsets ----
    for (int p = 0; p < 4; ++p) {
      int pos = p*256 + tid;
      int y = pos >> 5, x = pos & 31;
      int base = 2*y*72 + 2*x;
      hv2 a1[8];
      #pragma unroll
      for (int o = 0; o < 8; ++o) { a1[o].x = (_Float16)b1[16*hp+2*o]; a1[o].y = (_Float16)b1[16*hp+2*o+1]; }
      #pragma unroll
      for (int ic = 0; ic < 3; ++ic)
        #pragma unroll
        for (int ky = 0; ky < 3; ++ky)
          #pragma unroll
          for (int kx = 0; kx < 3; ++kx) {
            _Float16 hf = frHh[base + ic*4752 + ky*72 + kx + 3];
            hv2 vs; vs.x = hf; vs.y = hf;
            int k = ic*9 + ky*3 + kx;
            uint4 wa = ((uint4*)w1s)[k*4 + hp*2];
            uint4 wb = ((uint4*)w1s)[k*4 + hp*2 + 1];
            a1[0] = vs * u2h(wa.x) + a1[0];
            a1[1] = vs * u2h(wa.y) + a1[1];
            a1[2] = vs * u2h(wa.z) + a1[2];
            a1[3] = vs * u2h(wa.w) + a1[3];
            a1[4] = vs * u2h(wb.x) + a1[4];
            a1[5] = vs * u2h(wb.y) + a1[5];
            a1[6] = vs * u2h(wb.z) + a1[6];
            a1[7] = vs * u2h(wb.w) + a1[7];
          }
      unsigned r0 = h2u(relu2(a1[0])), r1 = h2u(relu2(a1[1]));
      unsigned r2 = h2u(relu2(a1[2])), r3 = h2u(relu2(a1[3]));
      unsigned r4 = h2u(relu2(a1[4])), r5 = h2u(relu2(a1[5]));
      unsigned r6 = h2u(relu2(a1[6])), r7 = h2u(relu2(a1[7]));
      int s = pos & 3;
      uint4 v0, v1;
      if (s & 1) { v0 = make_uint4(r2,r3,r0,r1); v1 = make_uint4(r6,r7,r4,r5); }
      else       { v0 = make_uint4(r0,r1,r2,r3); v1 = make_uint4(r4,r5,r6,r7); }
      int sl = (s >> 1) & 1;
      ((uint4*)buf0)[pos*2 + sl]     = v0;
      ((uint4*)buf0)[pos*2 + (1^sl)] = v1;
    }
    __syncthreads();
    // ---- conv2 half (MFMA): B-frags direct from L2 (2 x uint4 per kt) ----
    #pragma unroll
    for (int ky = 0; ky < 3; ++ky)
      #pragma unroll
      for (int kx = 0; kx < 3; ++kx) {
        int kt = ky*3 + kx;
        int bidx = ((hp*9 + kt)*64 + l)*2;
        uint4 q0 = w2f4[bidx];
        uint4 q1 = w2f4[bidx + 1];
        U2F bf[4];
        bf[0].u = make_uint2(q0.x, q0.y);
        bf[1].u = make_uint2(q0.z, q0.w);
        bf[2].u = make_uint2(q1.x, q1.y);
        bf[3].u = make_uint2(q1.z, q1.w);
        #pragma unroll
        for (int mi = 0; mi < 4; ++mi) {
          int mt = w*4 + mi;
          int iy = 2*mt - 1 + ky;
          if (iy >= 0) {
            int ix = 2*lc - 1 + kx;
            bool okx = (unsigned)ix < 32u;
            int pos1 = iy*32 + (okx ? ix : 0);
            U2F av; av.u = ((const uint2*)buf0)[pos1*4 + (kg ^ (pos1 & 3))];
            if (!okx) { av.u.x = 0u; av.u.y = 0u; }
            #pragma unroll
            for (int nt = 0; nt < 4; ++nt)
              acc2[mi][nt] = __builtin_amdgcn_mfma_f32_16x16x16f16(av.h, bf[nt].h, acc2[mi][nt], 0, 0, 0);
          }
        }
      }
    __syncthreads();   // act1 consumed; frH still intact for next hp
  }

  // ---- act2 (relu, swizzled ch-last fp16) into buf0; pre-stage conv3-B chunk0 into w3buf ----
  // (frH dead from here on; w3buf aliases it)
  {
    uint4 s0a = w3src[tid];
    uint4 s0b = w3src[256 + tid];
    _Float16* act2h = (_Float16*)buf0;
    #pragma unroll
    for (int mi = 0; mi < 4; ++mi)
      #pragma unroll
      for (int nt = 0; nt < 4; ++nt)
        #pragma unroll
        for (int i = 0; i < 4; ++i) {
          int pos = (w*4 + mi)*16 + 4*kg + i;
          int oc = nt*16 + lc;
          float vv = fmaxf(acc2[mi][nt][i], 0.f);
          int ocp = (((oc >> 2) ^ (pos & 7)) << 2) + (oc & 3);
          act2h[pos*64 + ocp] = (_Float16)vv;
        }
    ((uint4*)w3buf)[tid] = s0a;
    ((uint4*)w3buf)[256 + tid] = s0b;
  }

  f32x4 acc3[8];
  #pragma unroll
  for (int nt = 0; nt < 8; ++nt) { float bb = b3[nt*16 + lc]; acc3[nt] = (f32x4){bb, bb, bb, bb}; }
  const int y3 = (w*16 + lc) >> 3, x3 = lc & 7;
  __syncthreads();

  // ---- conv3 (MFMA): 18 half-chunks (2 K-tiles each), dbuf reg->LDS staging ----
  for (int cc = 0; cc < 18; ++cc) {
    uint4 st0, st1;
    if (cc < 17) {
      st0 = w3src[(cc+1)*512 + tid];
      st1 = w3src[(cc+1)*512 + 256 + tid];
    }
    int kyx = cc >> 1;
    int ky = kyx / 3, kx = kyx % 3;
    int iy = 2*y3 - 1 + ky, ix = 2*x3 - 1 + kx;
    bool ok = ((unsigned)iy < 16u) && ((unsigned)ix < 16u);
    int posIn = (ok ? iy : 0)*16 + (ok ? ix : 0);
    int sw = posIn & 7;
    const uint2* bvp = (const uint2*)w3buf + (cc & 1)*1024;
    #pragma unroll
    for (int k2 = 0; k2 < 2; ++k2) {
      int kt = 2*cc + k2;
      int icb = (kt & 3)*4 + kg;
      U2F av; av.u = ((const uint2*)buf0)[posIn*16 + (icb ^ sw)];
      if (!ok) { av.u.x = 0u; av.u.y = 0u; }
      #pragma unroll
      for (int nt = 0; nt < 8; ++nt) {
        U2F bv; bv.u = bvp[((k2*8 + nt)<<6) + l];
        acc3[nt] = __builtin_amdgcn_mfma_f32_16x16x16f16(av.h, bv.h, acc3[nt], 0, 0, 0);
      }
    }
    if (cc < 17) {
      ((uint4*)w3buf)[((cc+1)&1)*512 + tid] = st0;
      ((uint4*)w3buf)[((cc+1)&1)*512 + 256 + tid] = st1;
    }
    __syncthreads();
  }

  // ---- relu + spatial mean + fused encoder projection ----
  #pragma unroll
  for (int nt = 0; nt < 8; ++nt) {
    float s = 0.f;
    #pragma unroll
    for (int i = 0; i < 4; ++i) s += fmaxf(acc3[nt][i], 0.f);
    s += __shfl_xor(s, 16);
    s += __shfl_xor(s, 32);
    if (l < 16) fmp[w*128 + nt*16 + l] = s;
  }
  __syncthreads();
  if (tid < 128) {
    float s = fmp[tid] + fmp[128 + tid] + fmp[256 + tid] + fmp[384 + tid];
    fmp[tid] = s * (1.f/64.f);
  }
  __syncthreads();
  {
    float accx = ws[OFF_BF + tid];
    const float* wfT = ws + OFF_WFT;
    for (int m = 0; m < 128; ++m) accx = fmaf(fmp[m], wfT[m*256 + tid], accx);
    ws[OFF_XW + (t*B_SZ + b)*HID + tid] = accx;
  }
}

// ---------------- sequential LTC scan: 1 block per batch, fp16 reg-resident weights ----------------
__global__ __launch_bounds__(1024) void scan_kernel(
    const float* __restrict__ tau, const float* __restrict__ av,
    const float* __restrict__ h0,
    float* __restrict__ ws, float* __restrict__ outh)
{
  const int b = blockIdx.x;
  const int tid = threadIdx.x;
  const int j = tid & 255, q = tid >> 8;
  __shared__ float hf[256];
  __shared__ unsigned hp16[128];
  __shared__ float part[4][256];
  __shared__ float hbuf[16*256];

  uint4 wv[8];
  {
    const uint4* wp = (const uint4*)((const unsigned*)ws + OFF_WRP + (q*256 + j)*32);
    #pragma unroll
    for (int r = 0; r < 8; ++r) wv[r] = wp[r];
  }
  const float tinv = 1.f / tau[j];
  const float aj = av[j];
  const float* xw = ws + OFF_XW;
  float* hh = ws + OFF_HH;

  {
    float hv0 = h0[b*256 + j];
    float hvn = __shfl_xor(hv0, 1);
    if (q == 0) {
      hf[j] = hv0;
      if (!(j & 1)) hp16[j >> 1] = packh2f(hv0, hvn);
    }
  }
  float xw_pref = xw[(0*B_SZ + b)*HID + j];
  __syncthreads();

  for (int t = 0; t < T_STEPS; ++t) {
    float xwv = xw_pref;
    xw_pref = xw[((t+1)*B_SZ + b)*HID + j];
    hv2 acc = {(_Float16)0.f, (_Float16)0.f};
    const uint4* hq = (const uint4*)hp16 + q*8;
    #pragma unroll
    for (int r = 0; r < 8; ++r) {
      uint4 hvp = hq[r];
      acc = u2h(hvp.x) * u2h(wv[r].x) + acc;
      acc = u2h(hvp.y) * u2h(wv[r].y) + acc;
      acc = u2h(hvp.z) * u2h(wv[r].z) + acc;
      acc = u2h(hvp.w) * u2h(wv[r].w) + acc;
    }
    float hv0 = hf[j];
    part[q][j] = (float)acc.x + (float)acc.y;
    __syncthreads();
    float pre = part[0][j] + part[1][j] + part[2][j] + part[3][j] + xwv;
    float f = 1.f - 2.f / (1.f + __expf(2.f * pre));
    float hn = fmaf(0.1f, fmaf(-(tinv + f), hv0, f * aj), hv0);
    float hnn = __shfl_xor(hn, 1);
    if (q == 0) {
      hf[j] = hn;
      hbuf[(t & 15)*256 + j] = hn;
      if (!(j & 1)) hp16[j >> 1] = packh2f(hn, hnn);
    }
    __syncthreads();
    if ((t & 15) == 15) {
      int base = t - 15;
      int st = tid >> 6;
      int col = (tid & 63) << 2;
      *(float4*)(hh + ((base + st)*B_SZ + b)*HID + col) = *(float4*)(hbuf + st*256 + col);
    }
  }
  if (q == 0) outh[b*HID + j] = hf[j];
}

// ---------------- decoder MLP over all (t,b), parallel ----------------
__global__ __launch_bounds__(256) void dec_kernel(
    const float* __restrict__ db1, const float* __restrict__ db2,
    const float* __restrict__ db3, const float* __restrict__ ws,
    float* __restrict__ outc)
{
  const int bid = blockIdx.x;
  const int b = bid >> 8, t = bid & 255;
  const int tid = threadIdx.x;
  __shared__ float hloc[256];
  __shared__ float p1[2][128];
  __shared__ float y1s[128];
  __shared__ float p2[4][64];
  __shared__ float y2s[64];
  const float* hh  = ws + OFF_HH + (t*B_SZ + b)*HID;
  const float* d1T = ws + OFF_D1T;
  const float* d2T = ws + OFF_D2T;
  const float* d3T = ws + OFF_D3T;
  hloc[tid] = hh[tid];
  __syncthreads();
  {
    int i = tid & 127, hf = tid >> 7;
    float s = 0.f;
    for (int k = hf*128; k < hf*128 + 128; ++k) s = fmaf(hloc[k], d1T[k*128 + i], s);
    p1[hf][i] = s;
  }
  __syncthreads();
  if (tid < 128) y1s[tid] = fmaxf(p1[0][tid] + p1[1][tid] + db1[tid], 0.f);
  __syncthreads();
  {
    int i = tid & 63, r = tid >> 6;
    float s = 0.f;
    for (int k = r*32; k < r*32 + 32; ++k) s = fmaf(y1s[k], d2T[k*64 + i], s);
    p2[r][i] = s;
  }
  __syncthreads();
  if (tid < 64) y2s[tid] = fmaxf(p2[0][tid] + p2[1][tid] + p2[2][tid] + p2[3][tid] + db2[tid], 0.f);
  __syncthreads();
  if (tid < 6) {
    float s = db3[tid];
    for (int k = 0; k < 64; ++k) s = fmaf(y2s[k], d3T[k*6 + tid], s);
    outc[(b*T_STEPS + t)*6 + tid] = s;
  }
}

extern "C" void kernel_launch(void* const* d_in, const int* in_sizes, int n_in,
                              void* d_out, int out_size, void* d_ws, size_t ws_size,
                              hipStream_t stream)
{
  const float* frames = (const float*)d_in[0];
  const float* h0   = (const float*)d_in[1];
  const float* c1w  = (const float*)d_in[2];
  const float* c1b  = (const float*)d_in[3];
  const float* c2w  = (const float*)d_in[4];
  const float* c2b  = (const float*)d_in[5];
  const float* c3w  = (const float*)d_in[6];
  const float* c3b  = (const float*)d_in[7];
  const float* encw = (const float*)d_in[8];
  const float* encb = (const float*)d_in[9];
  const float* wr   = (const float*)d_in[10];
  const float* wi   = (const float*)d_in[11];
  const float* lb   = (const float*)d_in[12];
  const float* ltau = (const float*)d_in[13];
  const float* la   = (const float*)d_in[14];
  const float* dw1  = (const float*)d_in[15];
  const float* db1  = (const float*)d_in[16];
  const float* dw2  = (const float*)d_in[17];
  const float* db2  = (const float*)d_in[18];
  const float* dw3  = (const float*)d_in[19];
  const float* db3  = (const float*)d_in[20];
  float* out = (float*)d_out;
  float* ws  = (float*)d_ws;

  hipLaunchKernelGGL(prep_kernel, dim3(256), dim3(256), 0, stream,
                     c1w, c2w, c3w, encw, encb, wi, lb, wr, dw1, dw2, dw3, ws);
  hipLaunchKernelGGL(enc_kernel, dim3(2048), dim3(256), ENC_LDS_DW*4, stream,
                     frames, c1b, c2b, c3b, ws);
  hipLaunchKernelGGL(scan_kernel, dim3(B_SZ), dim3(1024), 0, stream,
                     ltau, la, h0, ws, out + 12288);
  hipLaunchKernelGGL(dec_kernel, dim3(2048), dim3(256), 0, stream,
                     db1, db2, db3, ws, out);
}